// Round 5
// baseline (218.388 us; speedup 1.0000x reference)
//
#include <hip/hip_runtime.h>
#include <cmath>

constexpr int kB  = 8;
constexpr int kC  = 256;
constexpr int kH  = 64;
constexpr int kW  = 64;
constexpr int kP  = kH * kW;    // 4096
constexpr int kL  = 80;
constexpr int kD  = 256;
constexpr int kNH = 8;

typedef short  short8 __attribute__((ext_vector_type(8)));
typedef float  f32x4  __attribute__((ext_vector_type(4)));
typedef unsigned short ushort_t;

__device__ __forceinline__ ushort_t f2bf(float f) {
  unsigned u = __builtin_bit_cast(unsigned, f);
  u += 0x7fffu + ((u >> 16) & 1u);
  return (ushort_t)(u >> 16);
}

__device__ __forceinline__ short8 pack8(float4 a, float4 b) {
  ushort_t tmp[8] = {f2bf(a.x), f2bf(a.y), f2bf(a.z), f2bf(a.w),
                     f2bf(b.x), f2bf(b.y), f2bf(b.z), f2bf(b.w)};
  return *(short8*)tmp;
}

// ---------------------------------------------------------------------------
// Kernel A: img (B, C, H, W) fp32 -> imgT (B, P, C) bf16 (NHWC cast).
// ---------------------------------------------------------------------------
__global__ __launch_bounds__(256) void transpose_img_kernel(
    const float* __restrict__ img, ushort_t* __restrict__ imgT) {
  __shared__ float Ls[64 * 67];
  const int b   = blockIdx.x;
  const int p0  = blockIdx.y * 64;
  const int ci0 = blockIdx.z * 64;
  const int t   = threadIdx.x;

  for (int e = t; e < 4096; e += 256) {
    int ci = e >> 6, px = e & 63;
    Ls[px * 67 + ci] = img[((size_t)(b * kC + ci0 + ci)) * kP + p0 + px];
  }
  __syncthreads();
  for (int u = t; u < 512; u += 256) {
    int px = u >> 3, cq = (u & 7) * 8;
    ushort_t tmp[8];
#pragma unroll
    for (int j = 0; j < 8; j++) tmp[j] = f2bf(Ls[px * 67 + cq + j]);
    *(uint4*)&imgT[((size_t)(b * kP + p0 + px)) * kC + ci0 + cq] = *(uint4*)tmp;
  }
}

// ---------------------------------------------------------------------------
// Kernel B: conv_w (co, ci, 3, 3) fp32 -> w2[tap][co][ci] bf16
// ---------------------------------------------------------------------------
__global__ __launch_bounds__(256) void transpose_w2_kernel(
    const float* __restrict__ cw, ushort_t* __restrict__ w2) {
  int idx = blockIdx.x * 256 + threadIdx.x;
  if (idx >= 9 * kC * kC) return;
  int ci  = idx & 255;
  int co  = (idx >> 8) & 255;
  int tap = idx >> 16;
  w2[idx] = f2bf(cw[(co * kC + ci) * 9 + tap]);
}

// ---------------------------------------------------------------------------
// Kernel 1 (MFMA): fused 1x1 conv + max-sigmoid attention. (R3-proven)
// ---------------------------------------------------------------------------
__global__ __launch_bounds__(256) void attn_mfma_kernel(
    const ushort_t* __restrict__ imgT,  // (B, P, C) bf16
    const float* __restrict__ text,     // (B, L, D) fp32
    const float* __restrict__ pw,       // (D, C) fp32
    const float* __restrict__ pb,
    const float* __restrict__ bias,
    const float* __restrict__ scale,
    float* __restrict__ attn_out) {     // (B, NH, P)
  __shared__ ushort_t SI[64 * 264];

  const int b    = blockIdx.x;
  const int p0   = blockIdx.y * 64;
  const int t    = threadIdx.x;
  const int w    = t >> 6;
  const int lane = t & 63;
  const int lr   = lane & 15;
  const int lq   = lane >> 4;
  const int d0   = w * 64;

  const ushort_t* imgTb = imgT + (size_t)b * kP * kC;

  f32x4 acc[4][4] = {};

  for (int kc = 0; kc < kC; kc += 32) {
    short8 afr[4], bfr[4];
#pragma unroll
    for (int mt = 0; mt < 4; mt++) {
      const float* p = pw + (size_t)(d0 + mt * 16 + lr) * kC + kc + lq * 8;
      afr[mt] = pack8(*(const float4*)p, *(const float4*)(p + 4));
    }
#pragma unroll
    for (int nt = 0; nt < 4; nt++)
      bfr[nt] = *(const short8*)&imgTb[(size_t)(p0 + nt * 16 + lr) * kC + kc + lq * 8];
#pragma unroll
    for (int mt = 0; mt < 4; mt++)
#pragma unroll
      for (int nt = 0; nt < 4; nt++)
        acc[mt][nt] = __builtin_amdgcn_mfma_f32_16x16x32_bf16(afr[mt], bfr[nt], acc[mt][nt], 0, 0, 0);
  }

#pragma unroll
  for (int mt = 0; mt < 4; mt++) {
    float4 pb4 = *(const float4*)(pb + d0 + mt * 16 + lq * 4);
#pragma unroll
    for (int nt = 0; nt < 4; nt++) {
      ushort_t v[4];
      v[0] = f2bf(acc[mt][nt][0] + pb4.x);
      v[1] = f2bf(acc[mt][nt][1] + pb4.y);
      v[2] = f2bf(acc[mt][nt][2] + pb4.z);
      v[3] = f2bf(acc[mt][nt][3] + pb4.w);
      *(ulonglong1*)&SI[(nt * 16 + lr) * 264 + d0 + mt * 16 + lq * 4] = *(ulonglong1*)v;
    }
  }
  // no barrier: wave w reads only the d-range it wrote (per-wave LDS ordering).

  const float* textb = text + (size_t)b * kL * kD;
#pragma unroll
  for (int lh = 0; lh < 2; lh++) {
    const int h = 2 * w + lh;
    const float bh = bias[h], sh = scale[h];
    short8 atok[5];
#pragma unroll
    for (int mt = 0; mt < 5; mt++) {
      const float* p = textb + (size_t)(mt * 16 + lr) * kD + h * 32 + lq * 8;
      atok[mt] = pack8(*(const float4*)p, *(const float4*)(p + 4));
    }
#pragma unroll
    for (int nt = 0; nt < 4; nt++) {
      short8 bfr2 = *(const short8*)&SI[(nt * 16 + lr) * 264 + h * 32 + lq * 8];
      float vmax = -3.4e38f;
#pragma unroll
      for (int mt = 0; mt < 5; mt++) {
        f32x4 z = {};
        f32x4 d = __builtin_amdgcn_mfma_f32_16x16x32_bf16(atok[mt], bfr2, z, 0, 0, 0);
        vmax = fmaxf(vmax, fmaxf(fmaxf(d[0], d[1]), fmaxf(d[2], d[3])));
      }
      vmax = fmaxf(vmax, __shfl_xor(vmax, 16));
      vmax = fmaxf(vmax, __shfl_xor(vmax, 32));
      if (lq == 0) {
        float lg = vmax * 0.17677669529663687f + bh;
        float a  = sh / (1.0f + expf(-lg));
        attn_out[((size_t)(b * kNH + h)) * kP + p0 + nt * 16 + lr] = a;
      }
    }
  }
}

// ---------------------------------------------------------------------------
// Kernel 2 (MFMA): 3x3 conv + BN + gate. Weights in LDS (4x cross-wave reuse);
// img B-frags direct from global (L1 absorbs tap redundancy). No padded image:
// row taps handled by wave-uniform skip; column edges by clamp + lane zeroing.
// LDS = 46 KB -> 3 blocks/CU.
// ---------------------------------------------------------------------------
__global__ __launch_bounds__(256, 3) void conv_mfma_kernel(
    const ushort_t* __restrict__ imgT,  // (B, P, C) bf16
    const ushort_t* __restrict__ w2,    // [tap][co][ci] bf16
    const float* __restrict__ gamma,
    const float* __restrict__ beta,
    const float* __restrict__ mean,
    const float* __restrict__ var,
    const float* __restrict__ attn,     // (B, NH, P) fp32
    float* __restrict__ out) {          // (B, C, H, W) fp32
  __shared__ ushort_t Wl[9 * 64 * 40];  // 46080 B

  const int co0 = blockIdx.x * 64;   // co fastest: co-blocks share img tile in L2
  const int b   = blockIdx.y;
  const int h0  = blockIdx.z * 4;
  const int t   = threadIdx.x;
  const int w   = t >> 6;
  const int lane = t & 63;
  const int lr  = lane & 15;
  const int lq  = lane >> 4;

  const ushort_t* imgTb = imgT + (size_t)b * kP * kC + lq * 8;

  f32x4 acc[4][4] = {};   // [mt=co/16][nt=px/16]

  for (int kc = 0; kc < kC; kc += 32) {
    __syncthreads();
    // stage weights: 9 taps x 64 co x 32 ci (stride 40 pad)
    {
      int e = t;
#pragma unroll
      for (int i = 0; i < 9; i++, e += 256) {
        int cq  = (e & 3) * 8;
        int co  = (e >> 2) & 63;
        int tap = e >> 8;
        uint4 v = *(const uint4*)&w2[((size_t)(tap * kC + co0 + co)) * kC + kc + cq];
        *(uint4*)&Wl[(tap * 64 + co) * 40 + cq] = v;
      }
    }
    __syncthreads();

    const int wbase = lr * 40 + lq * 8;
#pragma unroll
    for (int kh = 0; kh < 3; kh++) {
      const int r = h0 + w + kh - 1;        // wave-uniform
      if (r < 0 || r >= kH) continue;       // zero-pad row: contributes nothing
      const ushort_t* rowp = imgTb + (size_t)(r * kW) * kC + kc;
#pragma unroll
      for (int kw = 0; kw < 3; kw++) {
        const int tap = kh * 3 + kw;
        short8 bi[4];
#pragma unroll
        for (int nt = 0; nt < 4; nt++) {
          int col = nt * 16 + lr + kw - 1;
          if (kw == 0 && nt == 0) {
            int colc = col < 0 ? 0 : col;   // lane lr==0 clamps
            short8 v = *(const short8*)(rowp + (size_t)colc * kC);
            if (col < 0) v = (short8)0;     // zero-pad left col
            bi[nt] = v;
          } else if (kw == 2 && nt == 3) {
            int colc = col > 63 ? 63 : col; // lane lr==15 clamps
            short8 v = *(const short8*)(rowp + (size_t)colc * kC);
            if (col > 63) v = (short8)0;    // zero-pad right col
            bi[nt] = v;
          } else {
            bi[nt] = *(const short8*)(rowp + (size_t)col * kC);
          }
        }
        short8 aw[4];
#pragma unroll
        for (int mt = 0; mt < 4; mt++)
          aw[mt] = *(const short8*)&Wl[wbase + (tap * 64 + mt * 16) * 40];
#pragma unroll
        for (int mt = 0; mt < 4; mt++)
#pragma unroll
          for (int nt = 0; nt < 4; nt++)
            acc[mt][nt] = __builtin_amdgcn_mfma_f32_16x16x32_bf16(
                aw[mt], bi[nt], acc[mt][nt], 0, 0, 0);
      }
    }
  }

  const int h = h0 + w;
  float* outb = out + (size_t)b * kC * kP + h * kW;
#pragma unroll
  for (int mt = 0; mt < 4; mt++) {
    const int head = (co0 + mt * 16) >> 5;
    const float* arow = attn + ((size_t)(b * kNH + head)) * kP + h * kW;
    float inv_v[4], bb_v[4];
#pragma unroll
    for (int reg = 0; reg < 4; reg++) {
      int co = co0 + mt * 16 + lq * 4 + reg;
      float inv = gamma[co] * rsqrtf(var[co] + 1e-3f);
      inv_v[reg] = inv;
      bb_v[reg]  = beta[co] - mean[co] * inv;
    }
#pragma unroll
    for (int nt = 0; nt < 4; nt++) {
      const int col = nt * 16 + lr;
      const float av = arow[col];
#pragma unroll
      for (int reg = 0; reg < 4; reg++) {
        int co = co0 + mt * 16 + lq * 4 + reg;
        outb[(size_t)co * kP + col] = (acc[mt][nt][reg] * inv_v[reg] + bb_v[reg]) * av;
      }
    }
  }
}

// ---------------------------------------------------------------------------
extern "C" void kernel_launch(void* const* d_in, const int* in_sizes, int n_in,
                              void* d_out, int out_size, void* d_ws, size_t ws_size,
                              hipStream_t stream) {
  const float* img   = (const float*)d_in[0];
  const float* text  = (const float*)d_in[1];
  const float* pw    = (const float*)d_in[2];
  const float* pb    = (const float*)d_in[3];
  const float* bias  = (const float*)d_in[4];
  const float* scale = (const float*)d_in[5];
  const float* cw    = (const float*)d_in[6];
  const float* gam   = (const float*)d_in[7];
  const float* bet   = (const float*)d_in[8];
  const float* mea   = (const float*)d_in[9];
  const float* va    = (const float*)d_in[10];
  float* out = (float*)d_out;

  // workspace layout identical to R3 (proven within ws_size): 19,005,440 B
  char* ws = (char*)d_ws;
  float*    attn = (float*)ws;                                 // 1 MiB
  ushort_t* imgT = (ushort_t*)(ws + (1u << 20));               // 16 MiB
  ushort_t* w2   = (ushort_t*)(ws + (1u << 20) + (16u << 20)); // 1.125 MiB

  {
    dim3 grid(kB, kP / 64, kC / 64);
    transpose_img_kernel<<<grid, 256, 0, stream>>>(img, imgT);
  }
  transpose_w2_kernel<<<(9 * kC * kC + 255) / 256, 256, 0, stream>>>(cw, w2);

  {
    dim3 grid(kB, kP / 64);
    attn_mfma_kernel<<<grid, 256, 0, stream>>>(imgT, text, pw, pb, bias, scale, attn);
  }
  {
    dim3 grid(kC / 64, kB, kH / 4);
    conv_mfma_kernel<<<grid, 256, 0, stream>>>(imgT, w2, gam, bet, mea, va, attn, out);
  }
}

// Round 6
// 174.317 us; speedup vs baseline: 1.2528x; 1.2528x over previous
//
#include <hip/hip_runtime.h>
#include <cmath>

constexpr int kB  = 8;
constexpr int kC  = 256;
constexpr int kH  = 64;
constexpr int kW  = 64;
constexpr int kP  = kH * kW;    // 4096
constexpr int kL  = 80;
constexpr int kD  = 256;
constexpr int kNH = 8;

typedef short  short8 __attribute__((ext_vector_type(8)));
typedef float  f32x4  __attribute__((ext_vector_type(4)));
typedef unsigned short ushort_t;

__device__ __forceinline__ ushort_t f2bf(float f) {
  unsigned u = __builtin_bit_cast(unsigned, f);
  u += 0x7fffu + ((u >> 16) & 1u);
  return (ushort_t)(u >> 16);
}

__device__ __forceinline__ short8 pack8(float4 a, float4 b) {
  ushort_t tmp[8] = {f2bf(a.x), f2bf(a.y), f2bf(a.z), f2bf(a.w),
                     f2bf(b.x), f2bf(b.y), f2bf(b.z), f2bf(b.w)};
  return *(short8*)tmp;
}

// ---------------------------------------------------------------------------
// Kernel A: img (B, C, H, W) fp32 -> imgT (B, P, C) bf16 (NHWC cast).
// ---------------------------------------------------------------------------
__global__ __launch_bounds__(256) void transpose_img_kernel(
    const float* __restrict__ img, ushort_t* __restrict__ imgT) {
  __shared__ float Ls[64 * 67];
  const int b   = blockIdx.x;
  const int p0  = blockIdx.y * 64;
  const int ci0 = blockIdx.z * 64;
  const int t   = threadIdx.x;

  for (int e = t; e < 4096; e += 256) {
    int ci = e >> 6, px = e & 63;
    Ls[px * 67 + ci] = img[((size_t)(b * kC + ci0 + ci)) * kP + p0 + px];
  }
  __syncthreads();
  for (int u = t; u < 512; u += 256) {
    int px = u >> 3, cq = (u & 7) * 8;
    ushort_t tmp[8];
#pragma unroll
    for (int j = 0; j < 8; j++) tmp[j] = f2bf(Ls[px * 67 + cq + j]);
    *(uint4*)&imgT[((size_t)(b * kP + p0 + px)) * kC + ci0 + cq] = *(uint4*)tmp;
  }
}

// ---------------------------------------------------------------------------
// Kernel B (fused prep): conv_w -> w2[tap][co][ci] bf16, and pw -> pwb bf16.
// ---------------------------------------------------------------------------
__global__ __launch_bounds__(256) void prep_kernel(
    const float* __restrict__ cw, const float* __restrict__ pw,
    ushort_t* __restrict__ w2, ushort_t* __restrict__ pwb) {
  const int n_w2 = 9 * kC * kC;
  int idx = blockIdx.x * 256 + threadIdx.x;
  if (idx < n_w2) {
    int ci  = idx & 255;
    int co  = (idx >> 8) & 255;
    int tap = idx >> 16;
    w2[idx] = f2bf(cw[(co * kC + ci) * 9 + tap]);
  } else if (idx < n_w2 + kD * kC) {
    int r = idx - n_w2;
    pwb[r] = f2bf(pw[r]);   // same (D, C) layout, bf16
  }
}

// ---------------------------------------------------------------------------
// Kernel 1 (MFMA): fused 1x1 conv + max-sigmoid attention.
// pw now preconverted bf16 -> A-frags are raw short8 loads (no pack VALU).
// ---------------------------------------------------------------------------
__global__ __launch_bounds__(256) void attn_mfma_kernel(
    const ushort_t* __restrict__ imgT,  // (B, P, C) bf16
    const float* __restrict__ text,     // (B, L, D) fp32
    const ushort_t* __restrict__ pwb,   // (D, C) bf16
    const float* __restrict__ pb,
    const float* __restrict__ bias,
    const float* __restrict__ scale,
    float* __restrict__ attn_out) {     // (B, NH, P)
  __shared__ ushort_t SI[64 * 264];

  const int b    = blockIdx.x;
  const int p0   = blockIdx.y * 64;
  const int t    = threadIdx.x;
  const int w    = t >> 6;
  const int lane = t & 63;
  const int lr   = lane & 15;
  const int lq   = lane >> 4;
  const int d0   = w * 64;

  const ushort_t* imgTb = imgT + (size_t)b * kP * kC;

  f32x4 acc[4][4] = {};

  for (int kc = 0; kc < kC; kc += 32) {
    short8 afr[4], bfr[4];
#pragma unroll
    for (int mt = 0; mt < 4; mt++)
      afr[mt] = *(const short8*)&pwb[(size_t)(d0 + mt * 16 + lr) * kC + kc + lq * 8];
#pragma unroll
    for (int nt = 0; nt < 4; nt++)
      bfr[nt] = *(const short8*)&imgTb[(size_t)(p0 + nt * 16 + lr) * kC + kc + lq * 8];
#pragma unroll
    for (int mt = 0; mt < 4; mt++)
#pragma unroll
      for (int nt = 0; nt < 4; nt++)
        acc[mt][nt] = __builtin_amdgcn_mfma_f32_16x16x32_bf16(afr[mt], bfr[nt], acc[mt][nt], 0, 0, 0);
  }

#pragma unroll
  for (int mt = 0; mt < 4; mt++) {
    float4 pb4 = *(const float4*)(pb + d0 + mt * 16 + lq * 4);
#pragma unroll
    for (int nt = 0; nt < 4; nt++) {
      ushort_t v[4];
      v[0] = f2bf(acc[mt][nt][0] + pb4.x);
      v[1] = f2bf(acc[mt][nt][1] + pb4.y);
      v[2] = f2bf(acc[mt][nt][2] + pb4.z);
      v[3] = f2bf(acc[mt][nt][3] + pb4.w);
      *(ulonglong1*)&SI[(nt * 16 + lr) * 264 + d0 + mt * 16 + lq * 4] = *(ulonglong1*)v;
    }
  }
  // no barrier: wave w reads only the d-range it wrote (per-wave LDS ordering).

  const float* textb = text + (size_t)b * kL * kD;
#pragma unroll
  for (int lh = 0; lh < 2; lh++) {
    const int h = 2 * w + lh;
    const float bh = bias[h], sh = scale[h];
    short8 atok[5];
#pragma unroll
    for (int mt = 0; mt < 5; mt++) {
      const float* p = textb + (size_t)(mt * 16 + lr) * kD + h * 32 + lq * 8;
      atok[mt] = pack8(*(const float4*)p, *(const float4*)(p + 4));
    }
#pragma unroll
    for (int nt = 0; nt < 4; nt++) {
      short8 bfr2 = *(const short8*)&SI[(nt * 16 + lr) * 264 + h * 32 + lq * 8];
      float vmax = -3.4e38f;
#pragma unroll
      for (int mt = 0; mt < 5; mt++) {
        f32x4 z = {};
        f32x4 d = __builtin_amdgcn_mfma_f32_16x16x32_bf16(atok[mt], bfr2, z, 0, 0, 0);
        vmax = fmaxf(vmax, fmaxf(fmaxf(d[0], d[1]), fmaxf(d[2], d[3])));
      }
      vmax = fmaxf(vmax, __shfl_xor(vmax, 16));
      vmax = fmaxf(vmax, __shfl_xor(vmax, 32));
      if (lq == 0) {
        float lg = vmax * 0.17677669529663687f + bh;
        float a  = sh / (1.0f + expf(-lg));
        attn_out[((size_t)(b * kNH + h)) * kP + p0 + nt * 16 + lr] = a;
      }
    }
  }
}

// ---------------------------------------------------------------------------
// Kernel 2 (MFMA, R3-proven): 3x3 conv + BN + gate. Img halo + weights in LDS.
// ---------------------------------------------------------------------------
__global__ __launch_bounds__(256) void conv_mfma_kernel(
    const ushort_t* __restrict__ imgT,  // (B, P, C) bf16
    const ushort_t* __restrict__ w2,    // [tap][co][ci] bf16
    const float* __restrict__ gamma,
    const float* __restrict__ beta,
    const float* __restrict__ mean,
    const float* __restrict__ var,
    const float* __restrict__ attn,     // (B, NH, P) fp32
    float* __restrict__ out) {          // (B, C, H, W) fp32
  __shared__ ushort_t Al[6 * 66 * 40];  // 31680 B
  __shared__ ushort_t Wl[9 * 64 * 40];  // 46080 B

  const int b   = blockIdx.x;
  const int h0  = blockIdx.y * 4;
  const int co0 = blockIdx.z * 64;
  const int t   = threadIdx.x;
  const int w   = t >> 6;
  const int lane = t & 63;
  const int lr  = lane & 15;
  const int lq  = lane >> 4;

  const ushort_t* imgTb = imgT + (size_t)b * kP * kC;

  f32x4 acc[4][4] = {};

  for (int kc = 0; kc < kC; kc += 32) {
    __syncthreads();
    for (int e = t; e < 6 * 66 * 4; e += 256) {
      int r   = e / 264;
      int rem = e - r * 264;
      int c   = rem >> 2;
      int cq  = (rem & 3) * 8;
      int row = h0 - 1 + r;
      uint4 v = make_uint4(0, 0, 0, 0);
      if (row >= 0 && row < kH && c >= 1 && c <= 64) {
        int px = row * kW + (c - 1);
        v = *(const uint4*)&imgTb[(size_t)px * kC + kc + cq];
      }
      *(uint4*)&Al[(r * 66 + c) * 40 + cq] = v;
    }
    {
      int e = t;
#pragma unroll
      for (int i = 0; i < 9; i++, e += 256) {
        int cq  = (e & 3) * 8;
        int co  = (e >> 2) & 63;
        int tap = e >> 8;
        uint4 v = *(const uint4*)&w2[((size_t)(tap * kC + co0 + co)) * kC + kc + cq];
        *(uint4*)&Wl[(tap * 64 + co) * 40 + cq] = v;
      }
    }
    __syncthreads();

    const int abase = (w * 66 + lr) * 40 + lq * 8;
    const int wbase = lr * 40 + lq * 8;
#pragma unroll
    for (int tap = 0; tap < 9; tap++) {
      const int kh = tap / 3, kw = tap % 3;
      short8 bi[4];
#pragma unroll
      for (int nt = 0; nt < 4; nt++)
        bi[nt] = *(const short8*)&Al[abase + (kh * 66 + kw + nt * 16) * 40];
      short8 aw[4];
#pragma unroll
      for (int mt = 0; mt < 4; mt++)
        aw[mt] = *(const short8*)&Wl[wbase + (tap * 64 + mt * 16) * 40];
#pragma unroll
      for (int mt = 0; mt < 4; mt++)
#pragma unroll
        for (int nt = 0; nt < 4; nt++)
          acc[mt][nt] = __builtin_amdgcn_mfma_f32_16x16x32_bf16(
              aw[mt], bi[nt], acc[mt][nt], 0, 0, 0);
    }
  }

  const int h = h0 + w;
  float* outb = out + (size_t)b * kC * kP + h * kW;
#pragma unroll
  for (int mt = 0; mt < 4; mt++) {
    const int head = (co0 + mt * 16) >> 5;
    const float* arow = attn + ((size_t)(b * kNH + head)) * kP + h * kW;
    float inv_v[4], bb_v[4];
#pragma unroll
    for (int reg = 0; reg < 4; reg++) {
      int co = co0 + mt * 16 + lq * 4 + reg;
      float inv = gamma[co] * rsqrtf(var[co] + 1e-3f);
      inv_v[reg] = inv;
      bb_v[reg]  = beta[co] - mean[co] * inv;
    }
#pragma unroll
    for (int nt = 0; nt < 4; nt++) {
      const int col = nt * 16 + lr;
      const float av = arow[col];
#pragma unroll
      for (int reg = 0; reg < 4; reg++) {
        int co = co0 + mt * 16 + lq * 4 + reg;
        outb[(size_t)co * kP + col] = (acc[mt][nt][reg] * inv_v[reg] + bb_v[reg]) * av;
      }
    }
  }
}

// ---------------------------------------------------------------------------
extern "C" void kernel_launch(void* const* d_in, const int* in_sizes, int n_in,
                              void* d_out, int out_size, void* d_ws, size_t ws_size,
                              hipStream_t stream) {
  const float* img   = (const float*)d_in[0];
  const float* text  = (const float*)d_in[1];
  const float* pw    = (const float*)d_in[2];
  const float* pb    = (const float*)d_in[3];
  const float* bias  = (const float*)d_in[4];
  const float* scale = (const float*)d_in[5];
  const float* cw    = (const float*)d_in[6];
  const float* gam   = (const float*)d_in[7];
  const float* bet   = (const float*)d_in[8];
  const float* mea   = (const float*)d_in[9];
  const float* va    = (const float*)d_in[10];
  float* out = (float*)d_out;

  // workspace: attn 1 MiB | imgT 16 MiB | w2 1.125 MiB | pwb 128 KiB
  // total 19,136,512 B (R3-proven 19,005,440 + 128 KiB)
  char* ws = (char*)d_ws;
  float*    attn = (float*)ws;
  ushort_t* imgT = (ushort_t*)(ws + (1u << 20));
  ushort_t* w2   = (ushort_t*)(ws + (1u << 20) + (16u << 20));
  ushort_t* pwb  = (ushort_t*)(ws + (1u << 20) + (16u << 20) + 1179648u);

  {
    dim3 grid(kB, kP / 64, kC / 64);
    transpose_img_kernel<<<grid, 256, 0, stream>>>(img, imgT);
  }
  {
    int n = 9 * kC * kC + kD * kC;
    prep_kernel<<<(n + 255) / 256, 256, 0, stream>>>(cw, pw, w2, pwb);
  }
  {
    dim3 grid(kB, kP / 64);
    attn_mfma_kernel<<<grid, 256, 0, stream>>>(imgT, text, pwb, pb, bias, scale, attn);
  }
  {
    dim3 grid(kB, kH / 4, kC / 64);
    conv_mfma_kernel<<<grid, 256, 0, stream>>>(imgT, w2, gam, bet, mea, va, attn, out);
  }
}

// Round 8
// 159.499 us; speedup vs baseline: 1.3692x; 1.0929x over previous
//
#include <hip/hip_runtime.h>
#include <cmath>

constexpr int kB  = 8;
constexpr int kC  = 256;
constexpr int kH  = 64;
constexpr int kW  = 64;
constexpr int kP  = kH * kW;    // 4096
constexpr int kL  = 80;
constexpr int kD  = 256;
constexpr int kNH = 8;

typedef short  short8 __attribute__((ext_vector_type(8)));
typedef float  f32x4  __attribute__((ext_vector_type(4)));
typedef unsigned short ushort_t;

__device__ __forceinline__ ushort_t f2bf(float f) {
  unsigned u = __builtin_bit_cast(unsigned, f);
  u += 0x7fffu + ((u >> 16) & 1u);
  return (ushort_t)(u >> 16);
}

__device__ __forceinline__ short8 pack8(float4 a, float4 b) {
  ushort_t tmp[8] = {f2bf(a.x), f2bf(a.y), f2bf(a.z), f2bf(a.w),
                     f2bf(b.x), f2bf(b.y), f2bf(b.z), f2bf(b.w)};
  return *(short8*)tmp;
}

// ---------------------------------------------------------------------------
// Kernel B (fused prep): conv_w -> w2[tap][co][ci] bf16, and pw -> pwb bf16.
// ---------------------------------------------------------------------------
__global__ __launch_bounds__(256) void prep_kernel(
    const float* __restrict__ cw, const float* __restrict__ pw,
    ushort_t* __restrict__ w2, ushort_t* __restrict__ pwb) {
  const int n_w2 = 9 * kC * kC;
  int idx = blockIdx.x * 256 + threadIdx.x;
  if (idx < n_w2) {
    int ci  = idx & 255;
    int co  = (idx >> 8) & 255;
    int tap = idx >> 16;
    w2[idx] = f2bf(cw[(co * kC + ci) * 9 + tap]);
  } else if (idx < n_w2 + kD * kC) {
    int r = idx - n_w2;
    pwb[r] = f2bf(pw[r]);   // same (D, C) layout, bf16
  }
}

// ---------------------------------------------------------------------------
// Kernel 1 (MFMA, fused transpose): per k-chunk, stage 64px x 32ci of img
// (fp32 NCHW, coalesced over px) into LDS as bf16 [px][ci]; write the tile
// out as imgT (B,P,C) for the conv kernel; feed GEMM1 B-frags from LDS.
// Then max-sigmoid attention as before (SI round-trip, wave-private d range).
// ---------------------------------------------------------------------------
__global__ __launch_bounds__(256) void attn_mfma_kernel(
    const float* __restrict__ img,      // (B, C, H, W) fp32
    const float* __restrict__ text,     // (B, L, D) fp32
    const ushort_t* __restrict__ pwb,   // (D, C) bf16
    const float* __restrict__ pb,
    const float* __restrict__ bias,
    const float* __restrict__ scale,
    ushort_t* __restrict__ imgT,        // out: (B, P, C) bf16
    float* __restrict__ attn_out) {     // out: (B, NH, P)
  __shared__ ushort_t SB[64 * 40];      // transposed img chunk [px][ci pad 40]
  __shared__ ushort_t SI[64 * 264];     // i_feat [px][d pad 264]

  const int b    = blockIdx.x;
  const int p0   = blockIdx.y * 64;
  const int t    = threadIdx.x;
  const int w    = t >> 6;
  const int lane = t & 63;
  const int lr   = lane & 15;
  const int lq   = lane >> 4;
  const int d0   = w * 64;

  const float* imgb  = img  + (size_t)b * kC * kP + p0;
  ushort_t*    imgTb = imgT + (size_t)(b * kP + p0) * kC;

  f32x4 acc[4][4] = {};

  for (int kc = 0; kc < kC; kc += 32) {
    __syncthreads();
    // stage: 64 px x 32 ci, px-fastest lanes (coalesced global fp32 reads)
#pragma unroll
    for (int i = 0; i < 4; i++) {
      int e = t + i * 256;
      int px = e & 63, ci2 = (e >> 6) * 2;
      ushort_t u[2];
      u[0] = f2bf(imgb[(size_t)(kc + ci2)     * kP + px]);
      u[1] = f2bf(imgb[(size_t)(kc + ci2 + 1) * kP + px]);
      *(unsigned*)&SB[px * 40 + ci2] = *(unsigned*)u;
    }
    __syncthreads();
    // write-out imgT tile: 64 px x 32 ci = 256 uint4 units, one per thread
    {
      int px = t >> 2, cq = (t & 3) * 8;
      *(uint4*)&imgTb[(size_t)px * kC + kc + cq] = *(const uint4*)&SB[px * 40 + cq];
    }
    // fragments + MFMA
    short8 afr[4], bfr[4];
#pragma unroll
    for (int mt = 0; mt < 4; mt++)
      afr[mt] = *(const short8*)&pwb[(size_t)(d0 + mt * 16 + lr) * kC + kc + lq * 8];
#pragma unroll
    for (int nt = 0; nt < 4; nt++)
      bfr[nt] = *(const short8*)&SB[(nt * 16 + lr) * 40 + lq * 8];
#pragma unroll
    for (int mt = 0; mt < 4; mt++)
#pragma unroll
      for (int nt = 0; nt < 4; nt++)
        acc[mt][nt] = __builtin_amdgcn_mfma_f32_16x16x32_bf16(afr[mt], bfr[nt], acc[mt][nt], 0, 0, 0);
  }

  // i_feat (+bias) -> SI as bf16 [px][d]
#pragma unroll
  for (int mt = 0; mt < 4; mt++) {
    float4 pb4 = *(const float4*)(pb + d0 + mt * 16 + lq * 4);
#pragma unroll
    for (int nt = 0; nt < 4; nt++) {
      ushort_t v[4];
      v[0] = f2bf(acc[mt][nt][0] + pb4.x);
      v[1] = f2bf(acc[mt][nt][1] + pb4.y);
      v[2] = f2bf(acc[mt][nt][2] + pb4.z);
      v[3] = f2bf(acc[mt][nt][3] + pb4.w);
      *(ulonglong1*)&SI[(nt * 16 + lr) * 264 + d0 + mt * 16 + lq * 4] = *(ulonglong1*)v;
    }
  }
  // no barrier: wave w reads only the d-range it wrote (per-wave LDS ordering).

  const float* textb = text + (size_t)b * kL * kD;
#pragma unroll
  for (int lh = 0; lh < 2; lh++) {
    const int h = 2 * w + lh;
    const float bh = bias[h], sh = scale[h];
    short8 atok[5];
#pragma unroll
    for (int mt = 0; mt < 5; mt++) {
      const float* p = textb + (size_t)(mt * 16 + lr) * kD + h * 32 + lq * 8;
      atok[mt] = pack8(*(const float4*)p, *(const float4*)(p + 4));
    }
#pragma unroll
    for (int nt = 0; nt < 4; nt++) {
      short8 bfr2 = *(const short8*)&SI[(nt * 16 + lr) * 264 + h * 32 + lq * 8];
      float vmax = -3.4e38f;
#pragma unroll
      for (int mt = 0; mt < 5; mt++) {
        f32x4 z = {};
        f32x4 d = __builtin_amdgcn_mfma_f32_16x16x32_bf16(atok[mt], bfr2, z, 0, 0, 0);
        vmax = fmaxf(vmax, fmaxf(fmaxf(d[0], d[1]), fmaxf(d[2], d[3])));
      }
      vmax = fmaxf(vmax, __shfl_xor(vmax, 16));
      vmax = fmaxf(vmax, __shfl_xor(vmax, 32));
      if (lq == 0) {
        float lg = vmax * 0.17677669529663687f + bh;
        float a  = sh / (1.0f + expf(-lg));
        attn_out[((size_t)(b * kNH + h)) * kP + p0 + nt * 16 + lr] = a;
      }
    }
  }
}

// ---------------------------------------------------------------------------
// Kernel 2 (MFMA, R3-proven): 3x3 conv + BN + gate. Img halo + weights in LDS.
// ---------------------------------------------------------------------------
__global__ __launch_bounds__(256) void conv_mfma_kernel(
    const ushort_t* __restrict__ imgT,  // (B, P, C) bf16
    const ushort_t* __restrict__ w2,    // [tap][co][ci] bf16
    const float* __restrict__ gamma,
    const float* __restrict__ beta,
    const float* __restrict__ mean,
    const float* __restrict__ var,
    const float* __restrict__ attn,     // (B, NH, P) fp32
    float* __restrict__ out) {          // (B, C, H, W) fp32
  __shared__ ushort_t Al[6 * 66 * 40];  // 31680 B
  __shared__ ushort_t Wl[9 * 64 * 40];  // 46080 B

  const int b   = blockIdx.x;
  const int h0  = blockIdx.y * 4;
  const int co0 = blockIdx.z * 64;
  const int t   = threadIdx.x;
  const int w   = t >> 6;
  const int lane = t & 63;
  const int lr  = lane & 15;
  const int lq  = lane >> 4;

  const ushort_t* imgTb = imgT + (size_t)b * kP * kC;

  f32x4 acc[4][4] = {};

  for (int kc = 0; kc < kC; kc += 32) {
    __syncthreads();
    for (int e = t; e < 6 * 66 * 4; e += 256) {
      int r   = e / 264;
      int rem = e - r * 264;
      int c   = rem >> 2;
      int cq  = (rem & 3) * 8;
      int row = h0 - 1 + r;
      uint4 v = make_uint4(0, 0, 0, 0);
      if (row >= 0 && row < kH && c >= 1 && c <= 64) {
        int px = row * kW + (c - 1);
        v = *(const uint4*)&imgTb[(size_t)px * kC + kc + cq];
      }
      *(uint4*)&Al[(r * 66 + c) * 40 + cq] = v;
    }
    {
      int e = t;
#pragma unroll
      for (int i = 0; i < 9; i++, e += 256) {
        int cq  = (e & 3) * 8;
        int co  = (e >> 2) & 63;
        int tap = e >> 8;
        uint4 v = *(const uint4*)&w2[((size_t)(tap * kC + co0 + co)) * kC + kc + cq];
        *(uint4*)&Wl[(tap * 64 + co) * 40 + cq] = v;
      }
    }
    __syncthreads();

    const int abase = (w * 66 + lr) * 40 + lq * 8;
    const int wbase = lr * 40 + lq * 8;
#pragma unroll
    for (int tap = 0; tap < 9; tap++) {
      const int kh = tap / 3, kw = tap % 3;
      short8 bi[4];
#pragma unroll
      for (int nt = 0; nt < 4; nt++)
        bi[nt] = *(const short8*)&Al[abase + (kh * 66 + kw + nt * 16) * 40];
      short8 aw[4];
#pragma unroll
      for (int mt = 0; mt < 4; mt++)
        aw[mt] = *(const short8*)&Wl[wbase + (tap * 64 + mt * 16) * 40];
#pragma unroll
      for (int mt = 0; mt < 4; mt++)
#pragma unroll
        for (int nt = 0; nt < 4; nt++)
          acc[mt][nt] = __builtin_amdgcn_mfma_f32_16x16x32_bf16(
              aw[mt], bi[nt], acc[mt][nt], 0, 0, 0);
    }
  }

  const int h = h0 + w;
  float* outb = out + (size_t)b * kC * kP + h * kW;
#pragma unroll
  for (int mt = 0; mt < 4; mt++) {
    const int head = (co0 + mt * 16) >> 5;
    const float* arow = attn + ((size_t)(b * kNH + head)) * kP + h * kW;
    float inv_v[4], bb_v[4];
#pragma unroll
    for (int reg = 0; reg < 4; reg++) {
      int co = co0 + mt * 16 + lq * 4 + reg;
      float inv = gamma[co] * rsqrtf(var[co] + 1e-3f);
      inv_v[reg] = inv;
      bb_v[reg]  = beta[co] - mean[co] * inv;
    }
#pragma unroll
    for (int nt = 0; nt < 4; nt++) {
      const int col = nt * 16 + lr;
      const float av = arow[col];
#pragma unroll
      for (int reg = 0; reg < 4; reg++) {
        int co = co0 + mt * 16 + lq * 4 + reg;
        outb[(size_t)co * kP + col] = (acc[mt][nt][reg] * inv_v[reg] + bb_v[reg]) * av;
      }
    }
  }
}

// ---------------------------------------------------------------------------
extern "C" void kernel_launch(void* const* d_in, const int* in_sizes, int n_in,
                              void* d_out, int out_size, void* d_ws, size_t ws_size,
                              hipStream_t stream) {
  const float* img   = (const float*)d_in[0];
  const float* text  = (const float*)d_in[1];
  const float* pw    = (const float*)d_in[2];
  const float* pb    = (const float*)d_in[3];
  const float* bias  = (const float*)d_in[4];
  const float* scale = (const float*)d_in[5];
  const float* cw    = (const float*)d_in[6];
  const float* gam   = (const float*)d_in[7];
  const float* bet   = (const float*)d_in[8];
  const float* mea   = (const float*)d_in[9];
  const float* va    = (const float*)d_in[10];
  float* out = (float*)d_out;

  // workspace: attn 1 MiB | imgT 16 MiB | w2 1.125 MiB | pwb 128 KiB
  // total 19,136,512 B (R6-proven)
  char* ws = (char*)d_ws;
  float*    attn = (float*)ws;
  ushort_t* imgT = (ushort_t*)(ws + (1u << 20));
  ushort_t* w2   = (ushort_t*)(ws + (1u << 20) + (16u << 20));
  ushort_t* pwb  = (ushort_t*)(ws + (1u << 20) + (16u << 20) + 1179648u);

  {
    int n = 9 * kC * kC + kD * kC;
    prep_kernel<<<(n + 255) / 256, 256, 0, stream>>>(cw, pw, w2, pwb);
  }
  {
    dim3 grid(kB, kP / 64);
    attn_mfma_kernel<<<grid, 256, 0, stream>>>(img, text, pwb, pb, bias, scale, imgT, attn);
  }
  {
    dim3 grid(kB, kH / 4, kC / 64);
    conv_mfma_kernel<<<grid, 256, 0, stream>>>(imgT, w2, gam, bet, mea, va, attn, out);
  }
}

// Round 9
// 154.732 us; speedup vs baseline: 1.4114x; 1.0308x over previous
//
#include <hip/hip_runtime.h>
#include <cmath>

constexpr int kB  = 8;
constexpr int kC  = 256;
constexpr int kH  = 64;
constexpr int kW  = 64;
constexpr int kP  = kH * kW;    // 4096
constexpr int kL  = 80;
constexpr int kD  = 256;
constexpr int kNH = 8;

typedef short  short8 __attribute__((ext_vector_type(8)));
typedef float  f32x4  __attribute__((ext_vector_type(4)));
typedef unsigned short ushort_t;

__device__ __forceinline__ ushort_t f2bf(float f) {
  unsigned u = __builtin_bit_cast(unsigned, f);
  u += 0x7fffu + ((u >> 16) & 1u);
  return (ushort_t)(u >> 16);
}

__device__ __forceinline__ short8 pack8(float4 a, float4 b) {
  ushort_t tmp[8] = {f2bf(a.x), f2bf(a.y), f2bf(a.z), f2bf(a.w),
                     f2bf(b.x), f2bf(b.y), f2bf(b.z), f2bf(b.w)};
  return *(short8*)tmp;
}

// async global->LDS, 16 B per lane; LDS dest = wave-uniform base + lane*16
__device__ __forceinline__ void gl_lds16(const void* gp, void* lp) {
  __builtin_amdgcn_global_load_lds(
      (const __attribute__((address_space(1))) void*)gp,
      (__attribute__((address_space(3))) void*)lp,
      16, 0, 0);
}

// ---------------------------------------------------------------------------
// Kernel B (prep): conv_w -> w2s (chunk-major, co-block-major, XOR-swizzled
// 16B slots for lane-linear global_load_lds staging), and pw -> pwb bf16.
// w2s granule index G = ((chunk*4 + cob)*9 + tap)*256 + co_l*4 + s,
// slot s holds ci-granule g = s ^ (co_l & 3) of chunk (8 ci each).
// ---------------------------------------------------------------------------
__global__ __launch_bounds__(256) void prep_kernel(
    const float* __restrict__ cw, const float* __restrict__ pw,
    ushort_t* __restrict__ w2s, ushort_t* __restrict__ pwb) {
  const int n_w2 = 9 * kC * kC;   // 589824
  int idx = blockIdx.x * 256 + threadIdx.x;
  if (idx < n_w2) {
    int j    = idx & 7;
    int G    = idx >> 3;
    int s    = G & 3;
    int co_l = (G >> 2) & 63;
    int cbt  = G >> 8;            // cb*9 + tap, cb = chunk*4 + cob
    int tap  = cbt % 9;
    int cb   = cbt / 9;
    int chunk = cb >> 2, cob = cb & 3;
    int g    = s ^ (co_l & 3);
    int ci   = chunk * 32 + g * 8 + j;
    int co   = cob * 64 + co_l;
    w2s[idx] = f2bf(cw[(co * kC + ci) * 9 + tap]);
  } else if (idx < n_w2 + kD * kC) {
    int r = idx - n_w2;
    pwb[r] = f2bf(pw[r]);
  }
}

// ---------------------------------------------------------------------------
// Kernel 1 (MFMA, fused transpose): per k-chunk, stage 64px x 32ci of img
// (fp32 NCHW) into LDS bf16, write out as imgT, feed GEMM1 B-frags from LDS;
// then max-sigmoid attention (unchanged from R8).
// ---------------------------------------------------------------------------
__global__ __launch_bounds__(256) void attn_mfma_kernel(
    const float* __restrict__ img,      // (B, C, H, W) fp32
    const float* __restrict__ text,     // (B, L, D) fp32
    const ushort_t* __restrict__ pwb,   // (D, C) bf16
    const float* __restrict__ pb,
    const float* __restrict__ bias,
    const float* __restrict__ scale,
    ushort_t* __restrict__ imgT,        // out: (B, P, C) bf16
    float* __restrict__ attn_out) {     // out: (B, NH, P)
  __shared__ ushort_t SB[64 * 40];
  __shared__ ushort_t SI[64 * 264];

  const int b    = blockIdx.x;
  const int p0   = blockIdx.y * 64;
  const int t    = threadIdx.x;
  const int w    = t >> 6;
  const int lane = t & 63;
  const int lr   = lane & 15;
  const int lq   = lane >> 4;
  const int d0   = w * 64;

  const float* imgb  = img  + (size_t)b * kC * kP + p0;
  ushort_t*    imgTb = imgT + (size_t)(b * kP + p0) * kC;

  f32x4 acc[4][4] = {};

  for (int kc = 0; kc < kC; kc += 32) {
    __syncthreads();
#pragma unroll
    for (int i = 0; i < 4; i++) {
      int e = t + i * 256;
      int px = e & 63, ci2 = (e >> 6) * 2;
      ushort_t u[2];
      u[0] = f2bf(imgb[(size_t)(kc + ci2)     * kP + px]);
      u[1] = f2bf(imgb[(size_t)(kc + ci2 + 1) * kP + px]);
      *(unsigned*)&SB[px * 40 + ci2] = *(unsigned*)u;
    }
    __syncthreads();
    {
      int px = t >> 2, cq = (t & 3) * 8;
      *(uint4*)&imgTb[(size_t)px * kC + kc + cq] = *(const uint4*)&SB[px * 40 + cq];
    }
    short8 afr[4], bfr[4];
#pragma unroll
    for (int mt = 0; mt < 4; mt++)
      afr[mt] = *(const short8*)&pwb[(size_t)(d0 + mt * 16 + lr) * kC + kc + lq * 8];
#pragma unroll
    for (int nt = 0; nt < 4; nt++)
      bfr[nt] = *(const short8*)&SB[(nt * 16 + lr) * 40 + lq * 8];
#pragma unroll
    for (int mt = 0; mt < 4; mt++)
#pragma unroll
      for (int nt = 0; nt < 4; nt++)
        acc[mt][nt] = __builtin_amdgcn_mfma_f32_16x16x32_bf16(afr[mt], bfr[nt], acc[mt][nt], 0, 0, 0);
  }

#pragma unroll
  for (int mt = 0; mt < 4; mt++) {
    float4 pb4 = *(const float4*)(pb + d0 + mt * 16 + lq * 4);
#pragma unroll
    for (int nt = 0; nt < 4; nt++) {
      ushort_t v[4];
      v[0] = f2bf(acc[mt][nt][0] + pb4.x);
      v[1] = f2bf(acc[mt][nt][1] + pb4.y);
      v[2] = f2bf(acc[mt][nt][2] + pb4.z);
      v[3] = f2bf(acc[mt][nt][3] + pb4.w);
      *(ulonglong1*)&SI[(nt * 16 + lr) * 264 + d0 + mt * 16 + lq * 4] = *(ulonglong1*)v;
    }
  }
  // no barrier: wave w reads only the d-range it wrote.

  const float* textb = text + (size_t)b * kL * kD;
#pragma unroll
  for (int lh = 0; lh < 2; lh++) {
    const int h = 2 * w + lh;
    const float bh = bias[h], sh = scale[h];
    short8 atok[5];
#pragma unroll
    for (int mt = 0; mt < 5; mt++) {
      const float* p = textb + (size_t)(mt * 16 + lr) * kD + h * 32 + lq * 8;
      atok[mt] = pack8(*(const float4*)p, *(const float4*)(p + 4));
    }
#pragma unroll
    for (int nt = 0; nt < 4; nt++) {
      short8 bfr2 = *(const short8*)&SI[(nt * 16 + lr) * 264 + h * 32 + lq * 8];
      float vmax = -3.4e38f;
#pragma unroll
      for (int mt = 0; mt < 5; mt++) {
        f32x4 z = {};
        f32x4 d = __builtin_amdgcn_mfma_f32_16x16x32_bf16(atok[mt], bfr2, z, 0, 0, 0);
        vmax = fmaxf(vmax, fmaxf(fmaxf(d[0], d[1]), fmaxf(d[2], d[3])));
      }
      vmax = fmaxf(vmax, __shfl_xor(vmax, 16));
      vmax = fmaxf(vmax, __shfl_xor(vmax, 32));
      if (lq == 0) {
        float lg = vmax * 0.17677669529663687f + bh;
        float a  = sh / (1.0f + expf(-lg));
        attn_out[((size_t)(b * kNH + h)) * kP + p0 + nt * 16 + lr] = a;
      }
    }
  }
}

// ---------------------------------------------------------------------------
// Kernel 2 (MFMA + async staging): 3x3 conv + BN + gate.
// Al: [r 0..5][col 0..65][32 ci] no pad (col stride 64 B, bank-balanced).
// Wl: [tap][256 granules] XOR-swizzled (written lane-linear from w2s).
// Halo cols 0/65 zeroed once; invalid rows skipped per wave-uniform kh.
// 60 global_load_lds_dwordx4 per chunk, partitioned across 4 waves.
// ---------------------------------------------------------------------------
__global__ __launch_bounds__(256) void conv_mfma_kernel(
    const ushort_t* __restrict__ imgT,  // (B, P, C) bf16
    const ushort_t* __restrict__ w2s,   // swizzled weights (see prep)
    const float* __restrict__ gamma,
    const float* __restrict__ beta,
    const float* __restrict__ mean,
    const float* __restrict__ var,
    const float* __restrict__ attn,     // (B, NH, P) fp32
    float* __restrict__ out) {          // (B, C, H, W) fp32
  __shared__ ushort_t Al[6 * 66 * 32];  // 25344 B
  __shared__ ushort_t Wl[9 * 256 * 8];  // 36864 B

  const int b    = blockIdx.x;
  const int h0   = blockIdx.y * 4;
  const int cob  = blockIdx.z;          // co0 = cob*64
  const int co0  = cob * 64;
  const int t    = threadIdx.x;
  const int w    = t >> 6;
  const int lane = t & 63;
  const int lr   = lane & 15;
  const int lq   = lane >> 4;

  // zero halo cols 0 and 65 once (never overwritten by staging)
  if (t < 48) {
    int r = t >> 3, cc = (t >> 2) & 1, s4 = t & 3;
    int col = cc ? 65 : 0;
    *(uint4*)&Al[(r * 66 + col) * 32 + s4 * 8] = make_uint4(0, 0, 0, 0);
  }

  const ushort_t* imgTb = imgT + (size_t)b * kP * kC;

  f32x4 acc[4][4] = {};   // [mt=co/16][nt=px/16]

  for (int kc8 = 0; kc8 < 8; kc8++) {
    const int kc = kc8 * 32;
    const ushort_t* w2sb = w2s + (size_t)(kc8 * 4 + cob) * 9 * 2048;
    __syncthreads();
    // issue 60 wave-loads (24 img + 36 wgt), 15 per wave
    for (int j = w; j < 60; j += 4) {
      if (j < 24) {
        int r = j >> 2, q = j & 3;
        int rimg = h0 - 1 + r;
        if (rimg >= 0 && rimg < kH) {
          int colq = q * 16 + (lane >> 2);           // interior col 0..63
          int s    = lane & 3;
          const ushort_t* g = imgTb + ((size_t)(rimg * kW + colq)) * kC + kc + s * 8;
          gl_lds16(g, &Al[(r * 66 + 1) * 32 + q * 512]);
        }
      } else {
        int jj = j - 24, tap = jj >> 2, q = jj & 3;
        const ushort_t* g = w2sb + ((size_t)(tap * 256 + q * 64 + lane)) * 8;
        gl_lds16(g, &Wl[(tap * 256 + q * 64) * 8]);
      }
    }
    __syncthreads();

#pragma unroll
    for (int kh = 0; kh < 3; kh++) {
      const int rimg = h0 + w + kh - 1;              // wave-uniform
      if (rimg < 0 || rimg >= kH) continue;          // zero-pad row
      const int ar = (w + kh) * 66 * 32;
#pragma unroll
      for (int kw = 0; kw < 3; kw++) {
        const int tap = kh * 3 + kw;
        short8 bi[4];
#pragma unroll
        for (int nt = 0; nt < 4; nt++)
          bi[nt] = *(const short8*)&Al[ar + (kw + nt * 16 + lr) * 32 + lq * 8];
        short8 aw[4];
#pragma unroll
        for (int mt = 0; mt < 4; mt++)
          aw[mt] = *(const short8*)&Wl[(tap * 256 + (mt * 16 + lr) * 4 + (lq ^ (lr & 3))) * 8];
#pragma unroll
        for (int mt = 0; mt < 4; mt++)
#pragma unroll
          for (int nt = 0; nt < 4; nt++)
            acc[mt][nt] = __builtin_amdgcn_mfma_f32_16x16x32_bf16(
                aw[mt], bi[nt], acc[mt][nt], 0, 0, 0);
      }
    }
  }

  const int h = h0 + w;
  float* outb = out + (size_t)b * kC * kP + h * kW;
#pragma unroll
  for (int mt = 0; mt < 4; mt++) {
    const int head = (co0 + mt * 16) >> 5;
    const float* arow = attn + ((size_t)(b * kNH + head)) * kP + h * kW;
    float inv_v[4], bb_v[4];
#pragma unroll
    for (int reg = 0; reg < 4; reg++) {
      int co = co0 + mt * 16 + lq * 4 + reg;
      float inv = gamma[co] * rsqrtf(var[co] + 1e-3f);
      inv_v[reg] = inv;
      bb_v[reg]  = beta[co] - mean[co] * inv;
    }
#pragma unroll
    for (int nt = 0; nt < 4; nt++) {
      const int col = nt * 16 + lr;
      const float av = arow[col];
#pragma unroll
      for (int reg = 0; reg < 4; reg++) {
        int co = co0 + mt * 16 + lq * 4 + reg;
        outb[(size_t)co * kP + col] = (acc[mt][nt][reg] * inv_v[reg] + bb_v[reg]) * av;
      }
    }
  }
}

// ---------------------------------------------------------------------------
extern "C" void kernel_launch(void* const* d_in, const int* in_sizes, int n_in,
                              void* d_out, int out_size, void* d_ws, size_t ws_size,
                              hipStream_t stream) {
  const float* img   = (const float*)d_in[0];
  const float* text  = (const float*)d_in[1];
  const float* pw    = (const float*)d_in[2];
  const float* pb    = (const float*)d_in[3];
  const float* bias  = (const float*)d_in[4];
  const float* scale = (const float*)d_in[5];
  const float* cw    = (const float*)d_in[6];
  const float* gam   = (const float*)d_in[7];
  const float* bet   = (const float*)d_in[8];
  const float* mea   = (const float*)d_in[9];
  const float* va    = (const float*)d_in[10];
  float* out = (float*)d_out;

  // workspace: attn 1 MiB | imgT 16 MiB | w2s 1.125 MiB | pwb 128 KiB
  // total 19,136,512 B (R6/R8-proven)
  char* ws = (char*)d_ws;
  float*    attn = (float*)ws;
  ushort_t* imgT = (ushort_t*)(ws + (1u << 20));
  ushort_t* w2s  = (ushort_t*)(ws + (1u << 20) + (16u << 20));
  ushort_t* pwb  = (ushort_t*)(ws + (1u << 20) + (16u << 20) + 1179648u);

  {
    int n = 9 * kC * kC + kD * kC;
    prep_kernel<<<(n + 255) / 256, 256, 0, stream>>>(cw, pw, w2s, pwb);
  }
  {
    dim3 grid(kB, kP / 64);
    attn_mfma_kernel<<<grid, 256, 0, stream>>>(img, text, pwb, pb, bias, scale, imgT, attn);
  }
  {
    dim3 grid(kB, kH / 4, kC / 64);
    conv_mfma_kernel<<<grid, 256, 0, stream>>>(imgT, w2s, gam, bet, mea, va, attn, out);
  }
}